// Round 4
// baseline (53.812 us; speedup 1.0000x reference)
//
#include <hip/hip_runtime.h>

#define EPSILON_F 5.0f

// Native clang vector types: __builtin_nontemporal_load requires these
// (HIP_vector_type float4/int4 are rejected). Same 16B layout.
typedef float f32x4 __attribute__((ext_vector_type(4)));
typedef int   i32x4 __attribute__((ext_vector_type(4)));

// Pass 1: each wave processes chunks of 4 consecutive rows.
//  - one 16B broadcast load fetches 4 labels (non-temporal: streamed once)
//  - 4 feat 16B loads (non-temporal) + 4 means 16B loads (cached, L2-resident)
//  - reduced-shuffle reduction: 12 DS ops per chunk instead of 24:
//      2 butterfly stages per row (off=32,16) -> partials indexed by lane&15,
//      4-way row select per 16-lane group, 4 shared stages (off=8,4,2,1).
//    Each row's hinge is then counted 16x across the wave -> final scale 1/16.
__global__ __launch_bounds__(256) void ncl_partial_kernel(
    const float* __restrict__ feat,     // [B, 256]
    const float* __restrict__ means,    // [C, 256]
    const int* __restrict__ labels,     // [B]
    float* __restrict__ partials,       // [gridDim.x]
    int nchunks)                        // B / 4
{
    const int lane = threadIdx.x & 63;
    const int wave = threadIdx.x >> 6;
    const int gwave = blockIdx.x * (blockDim.x >> 6) + wave;
    const int nwaves = gridDim.x * (blockDim.x >> 6);
    const int grp = lane >> 4;          // which of the 4 rows this lane finishes

    float acc = 0.0f;
    for (int c = gwave; c < nchunks; c += nwaves) {
        const size_t rb = (size_t)c * 4;  // first row of this 4-row chunk
        const i32x4 lv = __builtin_nontemporal_load(
            reinterpret_cast<const i32x4*>(labels + rb));

        const float* fp = feat + rb * 256 + lane * 4;
        const f32x4 f0 = __builtin_nontemporal_load(reinterpret_cast<const f32x4*>(fp));
        const f32x4 f1 = __builtin_nontemporal_load(reinterpret_cast<const f32x4*>(fp + 256));
        const f32x4 f2 = __builtin_nontemporal_load(reinterpret_cast<const f32x4*>(fp + 512));
        const f32x4 f3 = __builtin_nontemporal_load(reinterpret_cast<const f32x4*>(fp + 768));

        const f32x4 m0 = *reinterpret_cast<const f32x4*>(means + (size_t)lv.x * 256 + lane * 4);
        const f32x4 m1 = *reinterpret_cast<const f32x4*>(means + (size_t)lv.y * 256 + lane * 4);
        const f32x4 m2 = *reinterpret_cast<const f32x4*>(means + (size_t)lv.z * 256 + lane * 4);
        const f32x4 m3 = *reinterpret_cast<const f32x4*>(means + (size_t)lv.w * 256 + lane * 4);

        float d0, d1, d2, d3;
        { f32x4 t = f0 - m0; d0 = t.x*t.x + t.y*t.y + t.z*t.z + t.w*t.w; }
        { f32x4 t = f1 - m1; d1 = t.x*t.x + t.y*t.y + t.z*t.z + t.w*t.w; }
        { f32x4 t = f2 - m2; d2 = t.x*t.x + t.y*t.y + t.z*t.z + t.w*t.w; }
        { f32x4 t = f3 - m3; d3 = t.x*t.x + t.y*t.y + t.z*t.z + t.w*t.w; }

        // stage 1+2: per-row butterflies; after these, each lane's d_r is the
        // sum over the 4 lanes sharing (lane & 15).
        d0 += __shfl_xor(d0, 32, 64); d1 += __shfl_xor(d1, 32, 64);
        d2 += __shfl_xor(d2, 32, 64); d3 += __shfl_xor(d3, 32, 64);
        d0 += __shfl_xor(d0, 16, 64); d1 += __shfl_xor(d1, 16, 64);
        d2 += __shfl_xor(d2, 16, 64); d3 += __shfl_xor(d3, 16, 64);

        // 16-lane group g takes ownership of row g (all 16 residues present)
        float x = (grp == 0) ? d0 : (grp == 1) ? d1 : (grp == 2) ? d2 : d3;

        // shared stages: finish all 4 rows at once (xor<16 stays in-group)
        x += __shfl_xor(x, 8, 64);
        x += __shfl_xor(x, 4, 64);
        x += __shfl_xor(x, 2, 64);
        x += __shfl_xor(x, 1, 64);

        // every lane in group g holds row g's full distance^2; hinge on all
        // lanes -> each row counted 16x (corrected by 1/16 at the end)
        acc += fmaxf(EPSILON_F - sqrtf(x), 0.0f);
    }

    // wave-reduce acc once per kernel (rows were counted 16x -> scale 1/16)
    #pragma unroll
    for (int off = 32; off; off >>= 1) acc += __shfl_xor(acc, off, 64);

    __shared__ float wsum[4];
    if (lane == 0) wsum[wave] = acc * 0.0625f;
    __syncthreads();
    if (threadIdx.x == 0)
        partials[blockIdx.x] = wsum[0] + wsum[1] + wsum[2] + wsum[3];
}

// Pass 2: deterministic reduce of block partials -> mean.
__global__ __launch_bounds__(256) void ncl_final_kernel(
    const float* __restrict__ partials, int n, float* __restrict__ out, float invB)
{
    float s = 0.0f;
    for (int i = threadIdx.x; i < n; i += 256) s += partials[i];
    #pragma unroll
    for (int off = 32; off; off >>= 1) s += __shfl_xor(s, off, 64);
    __shared__ float wsum[4];
    if ((threadIdx.x & 63) == 0) wsum[threadIdx.x >> 6] = s;
    __syncthreads();
    if (threadIdx.x == 0) out[0] = (wsum[0] + wsum[1] + wsum[2] + wsum[3]) * invB;
}

extern "C" void kernel_launch(void* const* d_in, const int* in_sizes, int n_in,
                              void* d_out, int out_size, void* d_ws, size_t ws_size,
                              hipStream_t stream)
{
    const float* feat   = (const float*)d_in[0];   // [B, 256] f32
    const float* means  = (const float*)d_in[1];   // [C, 256] f32
    const int*   labels = (const int*)d_in[2];     // [B] int
    float* out = (float*)d_out;

    const int B = in_sizes[0] / 256;
    const int NBLOCKS = 2048;
    float* partials = (float*)d_ws;  // 2048 floats = 8 KB scratch

    ncl_partial_kernel<<<NBLOCKS, 256, 0, stream>>>(feat, means, labels, partials, B / 4);
    ncl_final_kernel<<<1, 256, 0, stream>>>(partials, NBLOCKS, out, 1.0f / (float)B);
}

// Round 5
// 49.419 us; speedup vs baseline: 1.0889x; 1.0889x over previous
//
#include <hip/hip_runtime.h>

#define EPSILON_F 5.0f

// Pass 1: each wave processes chunks of 4 consecutive rows.
//  - one 16B broadcast int4 load fetches 4 labels
//  - 4 feat float4 loads + 4 means float4 loads, all plain cached loads
//    (R4 lesson: nontemporal loads cost ~10% here — nothing needed protecting
//    in L2, and nt demotes the feature stream's L2 handling)
//  - reduced-shuffle reduction: 12 DS ops per chunk instead of 24:
//      2 butterfly stages per row (off=32,16) -> partials indexed by lane&15,
//      4-way row select per 16-lane group, 4 shared stages (off=8,4,2,1).
//    Each row's hinge is then counted 16x across the wave -> final scale 1/16.
__global__ __launch_bounds__(256) void ncl_partial_kernel(
    const float* __restrict__ feat,     // [B, 256]
    const float* __restrict__ means,    // [C, 256]
    const int* __restrict__ labels,     // [B]
    float* __restrict__ partials,       // [gridDim.x]
    int nchunks)                        // B / 4
{
    const int lane = threadIdx.x & 63;
    const int wave = threadIdx.x >> 6;
    const int gwave = blockIdx.x * (blockDim.x >> 6) + wave;
    const int nwaves = gridDim.x * (blockDim.x >> 6);
    const int grp = lane >> 4;          // which of the 4 rows this lane finishes

    float acc = 0.0f;
    for (int c = gwave; c < nchunks; c += nwaves) {
        const size_t rb = (size_t)c * 4;  // first row of this 4-row chunk
        const int4 lv = *reinterpret_cast<const int4*>(labels + rb);

        const float* fp = feat + rb * 256 + lane * 4;
        const float4 f0 = *reinterpret_cast<const float4*>(fp);
        const float4 f1 = *reinterpret_cast<const float4*>(fp + 256);
        const float4 f2 = *reinterpret_cast<const float4*>(fp + 512);
        const float4 f3 = *reinterpret_cast<const float4*>(fp + 768);

        const float4 m0 = *reinterpret_cast<const float4*>(means + (size_t)lv.x * 256 + lane * 4);
        const float4 m1 = *reinterpret_cast<const float4*>(means + (size_t)lv.y * 256 + lane * 4);
        const float4 m2 = *reinterpret_cast<const float4*>(means + (size_t)lv.z * 256 + lane * 4);
        const float4 m3 = *reinterpret_cast<const float4*>(means + (size_t)lv.w * 256 + lane * 4);

        float d0, d1, d2, d3;
        { float x=f0.x-m0.x, y=f0.y-m0.y, z=f0.z-m0.z, w=f0.w-m0.w; d0 = x*x + y*y + z*z + w*w; }
        { float x=f1.x-m1.x, y=f1.y-m1.y, z=f1.z-m1.z, w=f1.w-m1.w; d1 = x*x + y*y + z*z + w*w; }
        { float x=f2.x-m2.x, y=f2.y-m2.y, z=f2.z-m2.z, w=f2.w-m2.w; d2 = x*x + y*y + z*z + w*w; }
        { float x=f3.x-m3.x, y=f3.y-m3.y, z=f3.z-m3.z, w=f3.w-m3.w; d3 = x*x + y*y + z*z + w*w; }

        // stage 1+2: per-row butterflies; after these, each lane's d_r is the
        // sum over the 4 lanes sharing (lane & 15).
        d0 += __shfl_xor(d0, 32, 64); d1 += __shfl_xor(d1, 32, 64);
        d2 += __shfl_xor(d2, 32, 64); d3 += __shfl_xor(d3, 32, 64);
        d0 += __shfl_xor(d0, 16, 64); d1 += __shfl_xor(d1, 16, 64);
        d2 += __shfl_xor(d2, 16, 64); d3 += __shfl_xor(d3, 16, 64);

        // 16-lane group g takes ownership of row g (all 16 residues present)
        float x = (grp == 0) ? d0 : (grp == 1) ? d1 : (grp == 2) ? d2 : d3;

        // shared stages: finish all 4 rows at once (xor<16 stays in-group)
        x += __shfl_xor(x, 8, 64);
        x += __shfl_xor(x, 4, 64);
        x += __shfl_xor(x, 2, 64);
        x += __shfl_xor(x, 1, 64);

        // every lane in group g holds row g's full distance^2; hinge on all
        // lanes -> each row counted 16x (corrected by 1/16 at the end)
        acc += fmaxf(EPSILON_F - sqrtf(x), 0.0f);
    }

    // wave-reduce acc once per kernel (rows were counted 16x -> scale 1/16)
    #pragma unroll
    for (int off = 32; off; off >>= 1) acc += __shfl_xor(acc, off, 64);

    __shared__ float wsum[4];
    if (lane == 0) wsum[wave] = acc * 0.0625f;
    __syncthreads();
    if (threadIdx.x == 0)
        partials[blockIdx.x] = wsum[0] + wsum[1] + wsum[2] + wsum[3];
}

// Pass 2: deterministic reduce of block partials -> mean.
__global__ __launch_bounds__(256) void ncl_final_kernel(
    const float* __restrict__ partials, int n, float* __restrict__ out, float invB)
{
    float s = 0.0f;
    for (int i = threadIdx.x; i < n; i += 256) s += partials[i];
    #pragma unroll
    for (int off = 32; off; off >>= 1) s += __shfl_xor(s, off, 64);
    __shared__ float wsum[4];
    if ((threadIdx.x & 63) == 0) wsum[threadIdx.x >> 6] = s;
    __syncthreads();
    if (threadIdx.x == 0) out[0] = (wsum[0] + wsum[1] + wsum[2] + wsum[3]) * invB;
}

extern "C" void kernel_launch(void* const* d_in, const int* in_sizes, int n_in,
                              void* d_out, int out_size, void* d_ws, size_t ws_size,
                              hipStream_t stream)
{
    const float* feat   = (const float*)d_in[0];   // [B, 256] f32
    const float* means  = (const float*)d_in[1];   // [C, 256] f32
    const int*   labels = (const int*)d_in[2];     // [B] int
    float* out = (float*)d_out;

    const int B = in_sizes[0] / 256;
    const int NBLOCKS = 2048;
    float* partials = (float*)d_ws;  // 2048 floats = 8 KB scratch

    ncl_partial_kernel<<<NBLOCKS, 256, 0, stream>>>(feat, means, labels, partials, B / 4);
    ncl_final_kernel<<<1, 256, 0, stream>>>(partials, NBLOCKS, out, 1.0f / (float)B);
}

// Round 6
// 48.385 us; speedup vs baseline: 1.1122x; 1.0214x over previous
//
#include <hip/hip_runtime.h>

#define EPSILON_F 5.0f

// Pass 1: each wave processes chunks of 8 consecutive rows (R6 probe: 2x MLP,
// half the label loads and shuffle phases per byte vs 4-row chunks).
//  - two 16B broadcast int4 loads fetch 8 labels
//  - 8 feat float4 loads + 8 means float4 loads, plain cached loads
//    (R4 lesson: nontemporal loads cost ~10% here)
//  - reduced-shuffle reduction, 3 DS ops per row:
//      2 butterfly stages per row (off=32,16) -> partials indexed by lane&15,
//      4-way row select per 16-lane group (twice: rows 0-3 and rows 4-7),
//      4 shared stages (off=8,4,2,1) finishing two independent row-groups.
//    Each row's hinge is counted 16x across the wave -> final scale 1/16.
__global__ __launch_bounds__(256) void ncl_partial_kernel(
    const float* __restrict__ feat,     // [B, 256]
    const float* __restrict__ means,    // [C, 256]
    const int* __restrict__ labels,     // [B]
    float* __restrict__ partials,       // [gridDim.x]
    int nchunks)                        // B / 8
{
    const int lane = threadIdx.x & 63;
    const int wave = threadIdx.x >> 6;
    const int gwave = blockIdx.x * (blockDim.x >> 6) + wave;
    const int nwaves = gridDim.x * (blockDim.x >> 6);
    const int grp = lane >> 4;          // which row of each 4-row group this lane finishes

    float acc = 0.0f;
    for (int c = gwave; c < nchunks; c += nwaves) {
        const size_t rb = (size_t)c * 8;  // first row of this 8-row chunk
        const int4 lva = *reinterpret_cast<const int4*>(labels + rb);
        const int4 lvb = *reinterpret_cast<const int4*>(labels + rb + 4);

        const float* fp = feat + rb * 256 + lane * 4;
        const float4 f0 = *reinterpret_cast<const float4*>(fp);
        const float4 f1 = *reinterpret_cast<const float4*>(fp + 256);
        const float4 f2 = *reinterpret_cast<const float4*>(fp + 512);
        const float4 f3 = *reinterpret_cast<const float4*>(fp + 768);
        const float4 f4 = *reinterpret_cast<const float4*>(fp + 1024);
        const float4 f5 = *reinterpret_cast<const float4*>(fp + 1280);
        const float4 f6 = *reinterpret_cast<const float4*>(fp + 1536);
        const float4 f7 = *reinterpret_cast<const float4*>(fp + 1792);

        const float4 m0 = *reinterpret_cast<const float4*>(means + (size_t)lva.x * 256 + lane * 4);
        const float4 m1 = *reinterpret_cast<const float4*>(means + (size_t)lva.y * 256 + lane * 4);
        const float4 m2 = *reinterpret_cast<const float4*>(means + (size_t)lva.z * 256 + lane * 4);
        const float4 m3 = *reinterpret_cast<const float4*>(means + (size_t)lva.w * 256 + lane * 4);
        const float4 m4 = *reinterpret_cast<const float4*>(means + (size_t)lvb.x * 256 + lane * 4);
        const float4 m5 = *reinterpret_cast<const float4*>(means + (size_t)lvb.y * 256 + lane * 4);
        const float4 m6 = *reinterpret_cast<const float4*>(means + (size_t)lvb.z * 256 + lane * 4);
        const float4 m7 = *reinterpret_cast<const float4*>(means + (size_t)lvb.w * 256 + lane * 4);

        float d0, d1, d2, d3, d4, d5, d6, d7;
        { float x=f0.x-m0.x, y=f0.y-m0.y, z=f0.z-m0.z, w=f0.w-m0.w; d0 = x*x + y*y + z*z + w*w; }
        { float x=f1.x-m1.x, y=f1.y-m1.y, z=f1.z-m1.z, w=f1.w-m1.w; d1 = x*x + y*y + z*z + w*w; }
        { float x=f2.x-m2.x, y=f2.y-m2.y, z=f2.z-m2.z, w=f2.w-m2.w; d2 = x*x + y*y + z*z + w*w; }
        { float x=f3.x-m3.x, y=f3.y-m3.y, z=f3.z-m3.z, w=f3.w-m3.w; d3 = x*x + y*y + z*z + w*w; }
        { float x=f4.x-m4.x, y=f4.y-m4.y, z=f4.z-m4.z, w=f4.w-m4.w; d4 = x*x + y*y + z*z + w*w; }
        { float x=f5.x-m5.x, y=f5.y-m5.y, z=f5.z-m5.z, w=f5.w-m5.w; d5 = x*x + y*y + z*z + w*w; }
        { float x=f6.x-m6.x, y=f6.y-m6.y, z=f6.z-m6.z, w=f6.w-m6.w; d6 = x*x + y*y + z*z + w*w; }
        { float x=f7.x-m7.x, y=f7.y-m7.y, z=f7.z-m7.z, w=f7.w-m7.w; d7 = x*x + y*y + z*z + w*w; }

        // stage 1+2: after these, each lane's d_r = sum over lanes sharing (lane & 15)
        d0 += __shfl_xor(d0, 32, 64); d1 += __shfl_xor(d1, 32, 64);
        d2 += __shfl_xor(d2, 32, 64); d3 += __shfl_xor(d3, 32, 64);
        d4 += __shfl_xor(d4, 32, 64); d5 += __shfl_xor(d5, 32, 64);
        d6 += __shfl_xor(d6, 32, 64); d7 += __shfl_xor(d7, 32, 64);
        d0 += __shfl_xor(d0, 16, 64); d1 += __shfl_xor(d1, 16, 64);
        d2 += __shfl_xor(d2, 16, 64); d3 += __shfl_xor(d3, 16, 64);
        d4 += __shfl_xor(d4, 16, 64); d5 += __shfl_xor(d5, 16, 64);
        d6 += __shfl_xor(d6, 16, 64); d7 += __shfl_xor(d7, 16, 64);

        // 16-lane group g owns row g (first group of 4) and row g+4 (second)
        float xa = (grp == 0) ? d0 : (grp == 1) ? d1 : (grp == 2) ? d2 : d3;
        float xb = (grp == 0) ? d4 : (grp == 1) ? d5 : (grp == 2) ? d6 : d7;

        // shared stages: two independent chains finish 8 rows in 8 DS ops
        xa += __shfl_xor(xa, 8, 64);  xb += __shfl_xor(xb, 8, 64);
        xa += __shfl_xor(xa, 4, 64);  xb += __shfl_xor(xb, 4, 64);
        xa += __shfl_xor(xa, 2, 64);  xb += __shfl_xor(xb, 2, 64);
        xa += __shfl_xor(xa, 1, 64);  xb += __shfl_xor(xb, 1, 64);

        // each row counted 16x (corrected by 1/16 at the end)
        acc += fmaxf(EPSILON_F - sqrtf(xa), 0.0f)
             + fmaxf(EPSILON_F - sqrtf(xb), 0.0f);
    }

    // wave-reduce acc once per kernel (rows were counted 16x -> scale 1/16)
    #pragma unroll
    for (int off = 32; off; off >>= 1) acc += __shfl_xor(acc, off, 64);

    __shared__ float wsum[4];
    if (lane == 0) wsum[wave] = acc * 0.0625f;
    __syncthreads();
    if (threadIdx.x == 0)
        partials[blockIdx.x] = wsum[0] + wsum[1] + wsum[2] + wsum[3];
}

// Pass 2: deterministic reduce of block partials -> mean.
__global__ __launch_bounds__(256) void ncl_final_kernel(
    const float* __restrict__ partials, int n, float* __restrict__ out, float invB)
{
    float s = 0.0f;
    for (int i = threadIdx.x; i < n; i += 256) s += partials[i];
    #pragma unroll
    for (int off = 32; off; off >>= 1) s += __shfl_xor(s, off, 64);
    __shared__ float wsum[4];
    if ((threadIdx.x & 63) == 0) wsum[threadIdx.x >> 6] = s;
    __syncthreads();
    if (threadIdx.x == 0) out[0] = (wsum[0] + wsum[1] + wsum[2] + wsum[3]) * invB;
}

extern "C" void kernel_launch(void* const* d_in, const int* in_sizes, int n_in,
                              void* d_out, int out_size, void* d_ws, size_t ws_size,
                              hipStream_t stream)
{
    const float* feat   = (const float*)d_in[0];   // [B, 256] f32
    const float* means  = (const float*)d_in[1];   // [C, 256] f32
    const int*   labels = (const int*)d_in[2];     // [B] int
    float* out = (float*)d_out;

    const int B = in_sizes[0] / 256;
    const int NBLOCKS = 2048;
    float* partials = (float*)d_ws;  // 2048 floats = 8 KB scratch

    ncl_partial_kernel<<<NBLOCKS, 256, 0, stream>>>(feat, means, labels, partials, B / 8);
    ncl_final_kernel<<<1, 256, 0, stream>>>(partials, NBLOCKS, out, 1.0f / (float)B);
}